// Round 2
// baseline (513.227 us; speedup 1.0000x reference)
//
#include <hip/hip_runtime.h>

#define KNBR 32
#define NPART 256

typedef float  fvec4 __attribute__((ext_vector_type(4)));
typedef int    ivec4 __attribute__((ext_vector_type(4)));

// ---------------- Pass 1: 256 partial sums of X (no atomics) ----------------
__global__ void __launch_bounds__(256) partial_sum_kernel(const float* __restrict__ X, int n,
                                                          double* __restrict__ part) {
    double local = 0.0;
    int stride = gridDim.x * blockDim.x;
    int n4 = n >> 2;
    const fvec4* X4 = (const fvec4*)X;
    for (int i = blockIdx.x * blockDim.x + threadIdx.x; i < n4; i += stride) {
        fvec4 v = X4[i];
        local += (double)((v.x + v.y) + (v.z + v.w));
    }
    for (int i = (n4 << 2) + blockIdx.x * blockDim.x + threadIdx.x; i < n; i += stride)
        local += (double)X[i];

    #pragma unroll
    for (int off = 32; off; off >>= 1)
        local += __shfl_down(local, off, 64);

    __shared__ double sm[4];
    int lane = threadIdx.x & 63, wid = threadIdx.x >> 6;
    if (lane == 0) sm[wid] = local;
    __syncthreads();
    if (threadIdx.x == 0)
        part[blockIdx.x] = (sm[0] + sm[1]) + (sm[2] + sm[3]);
}

// ---------------- Pass 2: one THREAD per row ----------------
// 8x16B nt loads for W and IDS (streamed once, keep L2 for X),
// 32 independent scalar gathers from X (L2-resident, 4 MB), serial FMA.
__global__ void __launch_bounds__(256) moran_kernel(const float* __restrict__ X,
                                                    const fvec4* __restrict__ W4,
                                                    const ivec4* __restrict__ I4,
                                                    const double* __restrict__ part,
                                                    float* __restrict__ out, int n) {
    // Recompute mean from the 256 partials (2 KB, L2-hit) — once per block.
    __shared__ double sm[4];
    {
        double p = part[threadIdx.x & (NPART - 1)];
        #pragma unroll
        for (int off = 32; off; off >>= 1) p += __shfl_down(p, off, 64);
        if ((threadIdx.x & 63) == 0) sm[threadIdx.x >> 6] = p;
    }
    __syncthreads();
    float mean = (float)(((sm[0] + sm[1]) + (sm[2] + sm[3])) * (1.0 / (double)n));

    int row = blockIdx.x * blockDim.x + threadIdx.x;
    if (row >= n) return;

    const fvec4* w  = W4 + (size_t)row * (KNBR / 4);
    const ivec4* id = I4 + (size_t)row * (KNBR / 4);

    float lag = 0.f, s2 = 0.f;
    #pragma unroll
    for (int c = 0; c < KNBR / 4; ++c) {
        ivec4 i4 = __builtin_nontemporal_load(&id[c]);
        fvec4 w4 = __builtin_nontemporal_load(&w[c]);
        float x0 = X[i4.x] - mean;
        float x1 = X[i4.y] - mean;
        float x2 = X[i4.z] - mean;
        float x3 = X[i4.w] - mean;
        lag += w4.x * x0 + w4.y * x1 + w4.z * x2 + w4.w * x3;
        s2  += w4.x * x0 * x0 + w4.y * x1 * x1 + w4.z * x2 * x2 + w4.w * x3 * x3;
    }
    float xa = X[row] - mean;
    __builtin_nontemporal_store(xa * lag * (float)(KNBR - 1) / s2, &out[row]);
}

extern "C" void kernel_launch(void* const* d_in, const int* in_sizes, int n_in,
                              void* d_out, int out_size, void* d_ws, size_t ws_size,
                              hipStream_t stream) {
    const float* X   = (const float*)d_in[0];
    const float* W   = (const float*)d_in[1];
    const int*   IDS = (const int*)d_in[2];
    float* out = (float*)d_out;
    int n = in_sizes[0];

    double* part = (double*)d_ws;  // 256 doubles, fully written by pass 1 every call

    partial_sum_kernel<<<NPART, 256, 0, stream>>>(X, n, part);

    int blocks = (n + 255) / 256;
    moran_kernel<<<blocks, 256, 0, stream>>>(X, (const fvec4*)W, (const ivec4*)IDS,
                                             part, out, n);
}

// Round 3
// 446.289 us; speedup vs baseline: 1.1500x; 1.1500x over previous
//
#include <hip/hip_runtime.h>

#define KNBR 32
#define NPART 256

typedef float  fvec4 __attribute__((ext_vector_type(4)));
typedef int    ivec4 __attribute__((ext_vector_type(4)));

// ---------------- Pass 1: 256 partial sums of X (no atomics) ----------------
__global__ void __launch_bounds__(256) partial_sum_kernel(const float* __restrict__ X, int n,
                                                          double* __restrict__ part) {
    double local = 0.0;
    int stride = gridDim.x * blockDim.x;
    int n4 = n >> 2;
    const fvec4* X4 = (const fvec4*)X;
    for (int i = blockIdx.x * blockDim.x + threadIdx.x; i < n4; i += stride) {
        fvec4 v = X4[i];
        local += (double)((v.x + v.y) + (v.z + v.w));
    }
    for (int i = (n4 << 2) + blockIdx.x * blockDim.x + threadIdx.x; i < n; i += stride)
        local += (double)X[i];

    #pragma unroll
    for (int off = 32; off; off >>= 1)
        local += __shfl_down(local, off, 64);

    __shared__ double sm[4];
    int lane = threadIdx.x & 63, wid = threadIdx.x >> 6;
    if (lane == 0) sm[wid] = local;
    __syncthreads();
    if (threadIdx.x == 0)
        part[blockIdx.x] = (sm[0] + sm[1]) + (sm[2] + sm[3]);
}

// ---------------- Pass 2: one THREAD per row ----------------
// Coalesced vector loads for W/IDS (plain, L1-cached); the 32 random X
// gathers go through agent-scope atomic loads -> global_load_dword sc0:
// L1 bypass (no 128B line fill per 4B use), still L2-cached.
__global__ void __launch_bounds__(256) moran_kernel(const float* __restrict__ X,
                                                    const fvec4* __restrict__ W4,
                                                    const ivec4* __restrict__ I4,
                                                    const double* __restrict__ part,
                                                    float* __restrict__ out, int n) {
    // Recompute mean from the 256 partials (2 KB, L2-hit) — once per block.
    __shared__ double sm[4];
    {
        double p = part[threadIdx.x & (NPART - 1)];
        #pragma unroll
        for (int off = 32; off; off >>= 1) p += __shfl_down(p, off, 64);
        if ((threadIdx.x & 63) == 0) sm[threadIdx.x >> 6] = p;
    }
    __syncthreads();
    float mean = (float)(((sm[0] + sm[1]) + (sm[2] + sm[3])) * (1.0 / (double)n));

    int row = blockIdx.x * blockDim.x + threadIdx.x;
    if (row >= n) return;

    const fvec4* w  = W4 + (size_t)row * (KNBR / 4);
    const ivec4* id = I4 + (size_t)row * (KNBR / 4);

    float lag = 0.f, s2 = 0.f;
    #pragma unroll
    for (int c = 0; c < KNBR / 4; ++c) {
        ivec4 i4 = id[c];
        fvec4 w4 = w[c];
        float x0 = __hip_atomic_load(&X[i4.x], __ATOMIC_RELAXED, __HIP_MEMORY_SCOPE_AGENT) - mean;
        float x1 = __hip_atomic_load(&X[i4.y], __ATOMIC_RELAXED, __HIP_MEMORY_SCOPE_AGENT) - mean;
        float x2 = __hip_atomic_load(&X[i4.z], __ATOMIC_RELAXED, __HIP_MEMORY_SCOPE_AGENT) - mean;
        float x3 = __hip_atomic_load(&X[i4.w], __ATOMIC_RELAXED, __HIP_MEMORY_SCOPE_AGENT) - mean;
        lag += w4.x * x0 + w4.y * x1 + w4.z * x2 + w4.w * x3;
        s2  += w4.x * x0 * x0 + w4.y * x1 * x1 + w4.z * x2 * x2 + w4.w * x3 * x3;
    }
    float xa = X[row] - mean;
    __builtin_nontemporal_store(xa * lag * (float)(KNBR - 1) / s2, &out[row]);
}

extern "C" void kernel_launch(void* const* d_in, const int* in_sizes, int n_in,
                              void* d_out, int out_size, void* d_ws, size_t ws_size,
                              hipStream_t stream) {
    const float* X   = (const float*)d_in[0];
    const float* W   = (const float*)d_in[1];
    const int*   IDS = (const int*)d_in[2];
    float* out = (float*)d_out;
    int n = in_sizes[0];

    double* part = (double*)d_ws;  // 256 doubles, fully written by pass 1 every call

    partial_sum_kernel<<<NPART, 256, 0, stream>>>(X, n, part);

    int blocks = (n + 255) / 256;
    moran_kernel<<<blocks, 256, 0, stream>>>(X, (const fvec4*)W, (const ivec4*)IDS,
                                             part, out, n);
}

// Round 4
// 428.488 us; speedup vs baseline: 1.1978x; 1.0415x over previous
//
#include <hip/hip_runtime.h>

#define KNBR 32
#define NPART 256

typedef float  fvec4 __attribute__((ext_vector_type(4)));
typedef int    ivec4 __attribute__((ext_vector_type(4)));

#define XGATHER(p) __hip_atomic_load((p), __ATOMIC_RELAXED, __HIP_MEMORY_SCOPE_AGENT)

// ---------------- Pass 1: 256 partial sums of X (no atomics) ----------------
__global__ void __launch_bounds__(256) partial_sum_kernel(const float* __restrict__ X, int n,
                                                          double* __restrict__ part) {
    double local = 0.0;
    int stride = gridDim.x * blockDim.x;
    int n4 = n >> 2;
    const fvec4* X4 = (const fvec4*)X;
    for (int i = blockIdx.x * blockDim.x + threadIdx.x; i < n4; i += stride) {
        fvec4 v = X4[i];
        local += (double)((v.x + v.y) + (v.z + v.w));
    }
    for (int i = (n4 << 2) + blockIdx.x * blockDim.x + threadIdx.x; i < n; i += stride)
        local += (double)X[i];

    #pragma unroll
    for (int off = 32; off; off >>= 1)
        local += __shfl_down(local, off, 64);

    __shared__ double sm[4];
    int lane = threadIdx.x & 63, wid = threadIdx.x >> 6;
    if (lane == 0) sm[wid] = local;
    __syncthreads();
    if (threadIdx.x == 0)
        part[blockIdx.x] = (sm[0] + sm[1]) + (sm[2] + sm[3]);
}

// ---------------- Pass 2: one THREAD per row, explicit 16-wide gather batches ----
// The gathers are the wall: latency-bound at ~300 cyc with too few in flight.
// Issue 16 independent sc0 gathers into registers before any waitcnt.
__global__ void __launch_bounds__(256) moran_kernel(const float* __restrict__ X,
                                                    const fvec4* __restrict__ W4,
                                                    const ivec4* __restrict__ I4,
                                                    const double* __restrict__ part,
                                                    float* __restrict__ out, int n) {
    // Recompute mean from the 256 partials (2 KB, L2-hit) — once per block.
    __shared__ double sm[4];
    {
        double p = part[threadIdx.x & (NPART - 1)];
        #pragma unroll
        for (int off = 32; off; off >>= 1) p += __shfl_down(p, off, 64);
        if ((threadIdx.x & 63) == 0) sm[threadIdx.x >> 6] = p;
    }
    __syncthreads();
    float mean = (float)(((sm[0] + sm[1]) + (sm[2] + sm[3])) * (1.0 / (double)n));

    int row = blockIdx.x * blockDim.x + threadIdx.x;
    if (row >= n) return;

    const ivec4* id = I4 + (size_t)row * (KNBR / 4);
    const fvec4* w  = W4 + (size_t)row * (KNBR / 4);

    float lag = 0.f, s2 = 0.f;
    #pragma unroll
    for (int half = 0; half < 2; ++half) {
        ivec4 i0 = id[half * 4 + 0];
        ivec4 i1 = id[half * 4 + 1];
        ivec4 i2 = id[half * 4 + 2];
        ivec4 i3 = id[half * 4 + 3];
        int idx[16] = { i0.x, i0.y, i0.z, i0.w,
                        i1.x, i1.y, i1.z, i1.w,
                        i2.x, i2.y, i2.z, i2.w,
                        i3.x, i3.y, i3.z, i3.w };
        float xg[16];
        #pragma unroll
        for (int t = 0; t < 16; ++t)
            xg[t] = XGATHER(&X[idx[t]]);          // 16 independent loads in flight

        fvec4 w0 = w[half * 4 + 0];
        fvec4 w1 = w[half * 4 + 1];
        fvec4 w2 = w[half * 4 + 2];
        fvec4 w3 = w[half * 4 + 3];
        float wv[16] = { w0.x, w0.y, w0.z, w0.w,
                         w1.x, w1.y, w1.z, w1.w,
                         w2.x, w2.y, w2.z, w2.w,
                         w3.x, w3.y, w3.z, w3.w };
        #pragma unroll
        for (int t = 0; t < 16; ++t) {
            float xn = xg[t] - mean;
            lag += wv[t] * xn;
            s2  += wv[t] * xn * xn;
        }
    }
    float xa = X[row] - mean;
    out[row] = xa * lag * (float)(KNBR - 1) / s2;
}

extern "C" void kernel_launch(void* const* d_in, const int* in_sizes, int n_in,
                              void* d_out, int out_size, void* d_ws, size_t ws_size,
                              hipStream_t stream) {
    const float* X   = (const float*)d_in[0];
    const float* W   = (const float*)d_in[1];
    const int*   IDS = (const int*)d_in[2];
    float* out = (float*)d_out;
    int n = in_sizes[0];

    double* part = (double*)d_ws;  // 256 doubles, fully written by pass 1 every call

    partial_sum_kernel<<<NPART, 256, 0, stream>>>(X, n, part);

    int blocks = (n + 255) / 256;
    moran_kernel<<<blocks, 256, 0, stream>>>(X, (const fvec4*)W, (const ivec4*)IDS,
                                             part, out, n);
}

// Round 5
// 427.917 us; speedup vs baseline: 1.1994x; 1.0013x over previous
//
#include <hip/hip_runtime.h>

#define KNBR 32
#define NPART 256

typedef float  fvec4 __attribute__((ext_vector_type(4)));
typedef int    ivec4 __attribute__((ext_vector_type(4)));

// ---------------- Pass 1: 256 partial sums of X (no atomics) ----------------
__global__ void __launch_bounds__(256) partial_sum_kernel(const float* __restrict__ X, int n,
                                                          double* __restrict__ part) {
    double local = 0.0;
    int stride = gridDim.x * blockDim.x;
    int n4 = n >> 2;
    const fvec4* X4 = (const fvec4*)X;
    for (int i = blockIdx.x * blockDim.x + threadIdx.x; i < n4; i += stride) {
        fvec4 v = X4[i];
        local += (double)((v.x + v.y) + (v.z + v.w));
    }
    for (int i = (n4 << 2) + blockIdx.x * blockDim.x + threadIdx.x; i < n; i += stride)
        local += (double)X[i];

    #pragma unroll
    for (int off = 32; off; off >>= 1)
        local += __shfl_down(local, off, 64);

    __shared__ double sm[4];
    int lane = threadIdx.x & 63, wid = threadIdx.x >> 6;
    if (lane == 0) sm[wid] = local;
    __syncthreads();
    if (threadIdx.x == 0)
        part[blockIdx.x & (NPART - 1)] = (sm[0] + sm[1]) + (sm[2] + sm[3]);
}

// ---------------- Pass 2: one THREAD per row ----------------
// The gather wall is latency x concurrency: compiler only keeps ~4 loads in
// flight (VGPR_Count=24 across R2-R4). Force 16 outstanding sc0 gathers per
// thread with a single asm block (saddr + 32-bit voffset form: 1 VGPR/addr).
__global__ void __launch_bounds__(256, 4) moran_kernel(const float* __restrict__ X,
                                                       const fvec4* __restrict__ W4,
                                                       const ivec4* __restrict__ I4,
                                                       const double* __restrict__ part,
                                                       float* __restrict__ out, int n) {
    // Recompute mean from the 256 partials (2 KB, L2-hit) — once per block.
    __shared__ double sm[4];
    {
        double p = part[threadIdx.x & (NPART - 1)];
        #pragma unroll
        for (int off = 32; off; off >>= 1) p += __shfl_down(p, off, 64);
        if ((threadIdx.x & 63) == 0) sm[threadIdx.x >> 6] = p;
    }
    __syncthreads();
    float mean = (float)(((sm[0] + sm[1]) + (sm[2] + sm[3])) * (1.0 / (double)n));

    int row = blockIdx.x * blockDim.x + threadIdx.x;
    if (row >= n) return;

    const ivec4* id = I4 + (size_t)row * (KNBR / 4);
    const fvec4* w  = W4 + (size_t)row * (KNBR / 4);

    float lag = 0.f, s2 = 0.f;
    #pragma unroll
    for (int half = 0; half < 2; ++half) {
        ivec4 i0 = id[half * 4 + 0];
        ivec4 i1 = id[half * 4 + 1];
        ivec4 i2 = id[half * 4 + 2];
        ivec4 i3 = id[half * 4 + 3];
        fvec4 w0 = w[half * 4 + 0];
        fvec4 w1 = w[half * 4 + 1];
        fvec4 w2 = w[half * 4 + 2];
        fvec4 w3 = w[half * 4 + 3];

        unsigned v0  = ((unsigned)i0.x) << 2, v1  = ((unsigned)i0.y) << 2,
                 v2  = ((unsigned)i0.z) << 2, v3  = ((unsigned)i0.w) << 2,
                 v4  = ((unsigned)i1.x) << 2, v5  = ((unsigned)i1.y) << 2,
                 v6  = ((unsigned)i1.z) << 2, v7  = ((unsigned)i1.w) << 2,
                 v8  = ((unsigned)i2.x) << 2, v9  = ((unsigned)i2.y) << 2,
                 v10 = ((unsigned)i2.z) << 2, v11 = ((unsigned)i2.w) << 2,
                 v12 = ((unsigned)i3.x) << 2, v13 = ((unsigned)i3.y) << 2,
                 v14 = ((unsigned)i3.z) << 2, v15 = ((unsigned)i3.w) << 2;

        float x0, x1, x2, x3, x4, x5, x6, x7, x8, x9, x10, x11, x12, x13, x14, x15;
        // 16 independent L1-bypassing gathers, all in flight before one wait.
        asm volatile(
            "global_load_dword %0, %16, %32 sc0\n\t"
            "global_load_dword %1, %17, %32 sc0\n\t"
            "global_load_dword %2, %18, %32 sc0\n\t"
            "global_load_dword %3, %19, %32 sc0\n\t"
            "global_load_dword %4, %20, %32 sc0\n\t"
            "global_load_dword %5, %21, %32 sc0\n\t"
            "global_load_dword %6, %22, %32 sc0\n\t"
            "global_load_dword %7, %23, %32 sc0\n\t"
            "global_load_dword %8, %24, %32 sc0\n\t"
            "global_load_dword %9, %25, %32 sc0\n\t"
            "global_load_dword %10, %26, %32 sc0\n\t"
            "global_load_dword %11, %27, %32 sc0\n\t"
            "global_load_dword %12, %28, %32 sc0\n\t"
            "global_load_dword %13, %29, %32 sc0\n\t"
            "global_load_dword %14, %30, %32 sc0\n\t"
            "global_load_dword %15, %31, %32 sc0\n\t"
            "s_waitcnt vmcnt(0)"
            : "=&v"(x0), "=&v"(x1), "=&v"(x2), "=&v"(x3),
              "=&v"(x4), "=&v"(x5), "=&v"(x6), "=&v"(x7),
              "=&v"(x8), "=&v"(x9), "=&v"(x10), "=&v"(x11),
              "=&v"(x12), "=&v"(x13), "=&v"(x14), "=&v"(x15)
            : "v"(v0), "v"(v1), "v"(v2), "v"(v3),
              "v"(v4), "v"(v5), "v"(v6), "v"(v7),
              "v"(v8), "v"(v9), "v"(v10), "v"(v11),
              "v"(v12), "v"(v13), "v"(v14), "v"(v15),
              "s"(X));

        float xg[16] = { x0, x1, x2, x3, x4, x5, x6, x7,
                         x8, x9, x10, x11, x12, x13, x14, x15 };
        float wv[16] = { w0.x, w0.y, w0.z, w0.w,
                         w1.x, w1.y, w1.z, w1.w,
                         w2.x, w2.y, w2.z, w2.w,
                         w3.x, w3.y, w3.z, w3.w };
        #pragma unroll
        for (int t = 0; t < 16; ++t) {
            float xn = xg[t] - mean;
            lag += wv[t] * xn;
            s2  += wv[t] * xn * xn;
        }
    }
    float xa = X[row] - mean;
    out[row] = xa * lag * (float)(KNBR - 1) / s2;
}

extern "C" void kernel_launch(void* const* d_in, const int* in_sizes, int n_in,
                              void* d_out, int out_size, void* d_ws, size_t ws_size,
                              hipStream_t stream) {
    const float* X   = (const float*)d_in[0];
    const float* W   = (const float*)d_in[1];
    const int*   IDS = (const int*)d_in[2];
    float* out = (float*)d_out;
    int n = in_sizes[0];

    double* part = (double*)d_ws;  // 256 doubles, each written (last-wins) every call

    partial_sum_kernel<<<NPART, 256, 0, stream>>>(X, n, part);

    int blocks = (n + 255) / 256;
    moran_kernel<<<blocks, 256, 0, stream>>>(X, (const fvec4*)W, (const ivec4*)IDS,
                                             part, out, n);
}